// Round 2
// baseline (419.058 us; speedup 1.0000x reference)
//
#include <hip/hip_runtime.h>
#include <cstddef>
#include <cstdint>

#define NH 16
#define HD 64
#define SLEN 1024
#define NB 64
#define DMODEL 1024

#define DOT4_ACC(acc, k, q) \
  acc = fmaf((k).x, (q).x, fmaf((k).y, (q).y, fmaf((k).z, (q).z, fmaf((k).w, (q).w, (acc)))))

#define FMA4_BCAST(accv, qv, w0_, w1_, w2_, w3_) do { \
  (accv).x = fmaf((qv).x, (w0_).x, fmaf((qv).y, (w1_).x, fmaf((qv).z, (w2_).x, fmaf((qv).w, (w3_).x, (accv).x)))); \
  (accv).y = fmaf((qv).x, (w0_).y, fmaf((qv).y, (w1_).y, fmaf((qv).z, (w2_).y, fmaf((qv).w, (w3_).y, (accv).y)))); \
  (accv).z = fmaf((qv).x, (w0_).z, fmaf((qv).y, (w1_).z, fmaf((qv).z, (w2_).z, fmaf((qv).w, (w3_).z, (accv).z)))); \
  (accv).w = fmaf((qv).x, (w0_).w, fmaf((qv).y, (w1_).w, fmaf((qv).z, (w2_).w, fmaf((qv).w, (w3_).w, (accv).w)))); \
} while (0)

__device__ __forceinline__ float wred_sum(float v) {
#pragma unroll
  for (int off = 32; off; off >>= 1) v += __shfl_xor(v, off, 64);
  return v;
}

// K0: qp[b][j] = sum_c query[b][c] * Wq[j][c].  One wave per j, Wq row in regs,
// loop b with full-wave shuffle reduction.
__global__ __launch_bounds__(256) void k0_qp(const float* __restrict__ query,
                                             const float* __restrict__ Wq,
                                             float* __restrict__ qp) {
  const int tid = threadIdx.x;
  const int w = tid >> 6, l = tid & 63;
  const int j = blockIdx.x * 4 + w;  // 0..1023
  const float4* wr = reinterpret_cast<const float4*>(Wq + (size_t)j * DMODEL) + l * 4;
  const float4 w0 = wr[0], w1 = wr[1], w2 = wr[2], w3 = wr[3];
  for (int b = 0; b < NB; ++b) {
    const float4* qr = reinterpret_cast<const float4*>(query + (size_t)b * DMODEL) + l * 4;
    float4 q0 = qr[0], q1 = qr[1], q2 = qr[2], q3 = qr[3];
    float s = 0.f;
    DOT4_ACC(s, w0, q0); DOT4_ACC(s, w1, q1); DOT4_ACC(s, w2, q2); DOT4_ACC(s, w3, q3);
    s = wred_sum(s);
    if (l == 0) qp[(size_t)b * DMODEL + j] = s;
  }
}

// K1: qt[b][h][m] = sum_d qp[b][h*64+d] * Wk[h*64+d][m].
// Block = (h, 8 b's). Threads parallel over m (coalesced Wk rows), qp broadcast from LDS.
__global__ __launch_bounds__(256) void k1_qt(const float* __restrict__ qp,
                                             const float* __restrict__ Wk,
                                             float* __restrict__ qt) {
  __shared__ __align__(16) float qpl[8][HD];
  const int h = blockIdx.x & 15;
  const int b0 = (blockIdx.x >> 4) * 8;
  const int tid = threadIdx.x;
  for (int f = tid; f < 8 * HD; f += 256) {
    int bi = f >> 6, d = f & 63;
    qpl[bi][d] = qp[(size_t)(b0 + bi) * DMODEL + h * HD + d];
  }
  __syncthreads();
  const int m4 = tid * 4;
  float4 acc[8];
#pragma unroll
  for (int i = 0; i < 8; ++i) acc[i] = make_float4(0.f, 0.f, 0.f, 0.f);
  const float* wbase = Wk + (size_t)(h * HD) * DMODEL + m4;
  for (int d = 0; d < HD; d += 4) {
    float4 wk0 = *reinterpret_cast<const float4*>(wbase + (size_t)(d + 0) * DMODEL);
    float4 wk1 = *reinterpret_cast<const float4*>(wbase + (size_t)(d + 1) * DMODEL);
    float4 wk2 = *reinterpret_cast<const float4*>(wbase + (size_t)(d + 2) * DMODEL);
    float4 wk3 = *reinterpret_cast<const float4*>(wbase + (size_t)(d + 3) * DMODEL);
#pragma unroll
    for (int bi = 0; bi < 8; ++bi) {
      float4 q = *reinterpret_cast<const float4*>(&qpl[bi][d]);
      FMA4_BCAST(acc[bi], q, wk0, wk1, wk2, wk3);
    }
  }
#pragma unroll
  for (int bi = 0; bi < 8; ++bi)
    *reinterpret_cast<float4*>(qt + ((size_t)(b0 + bi) * NH + h) * DMODEL + m4) = acc[bi];
}

// K2: sc[b][h][s] = (1/8) * sum_m qt[b][h][m] * keys[s][b][m].
// Block = (b, 128 s). Thread tile: 2 s x 4 h. Streams keys once (256 MiB).
__global__ __launch_bounds__(256) void k2_scores(const float* __restrict__ keys,
                                                 const float* __restrict__ qt,
                                                 float* __restrict__ sc) {
  const int b = blockIdx.x & 63;
  const int st = blockIdx.x >> 6;  // 0..7
  const int tid = threadIdx.x, w = tid >> 6, l = tid & 63;
  const int hg = l & 3, sg = l >> 2;
  const int s0 = st * 128 + w * 32 + sg * 2;
  const float* k0p = keys + ((size_t)s0 * NB + b) * DMODEL;
  const float* k1p = k0p + (size_t)NB * DMODEL;
  const float* q0p = qt + ((size_t)b * NH + hg * 4 + 0) * DMODEL;
  const float* q1p = q0p + DMODEL;
  const float* q2p = q0p + 2 * DMODEL;
  const float* q3p = q0p + 3 * DMODEL;
  float a00 = 0.f, a01 = 0.f, a02 = 0.f, a03 = 0.f;
  float a10 = 0.f, a11 = 0.f, a12 = 0.f, a13 = 0.f;
  for (int m = 0; m < DMODEL; m += 4) {
    float4 ka = *reinterpret_cast<const float4*>(k0p + m);
    float4 kb = *reinterpret_cast<const float4*>(k1p + m);
    float4 qa = *reinterpret_cast<const float4*>(q0p + m);
    float4 qb = *reinterpret_cast<const float4*>(q1p + m);
    float4 qc = *reinterpret_cast<const float4*>(q2p + m);
    float4 qd = *reinterpret_cast<const float4*>(q3p + m);
    DOT4_ACC(a00, ka, qa); DOT4_ACC(a01, ka, qb); DOT4_ACC(a02, ka, qc); DOT4_ACC(a03, ka, qd);
    DOT4_ACC(a10, kb, qa); DOT4_ACC(a11, kb, qb); DOT4_ACC(a12, kb, qc); DOT4_ACC(a13, kb, qd);
  }
  const float scale = 0.125f;  // 1/sqrt(64)
  float* o0 = sc + ((size_t)b * NH + hg * 4 + 0) * SLEN + s0;
  float* o1 = sc + ((size_t)b * NH + hg * 4 + 1) * SLEN + s0;
  float* o2 = sc + ((size_t)b * NH + hg * 4 + 2) * SLEN + s0;
  float* o3 = sc + ((size_t)b * NH + hg * 4 + 3) * SLEN + s0;
  o0[0] = a00 * scale; o0[1] = a10 * scale;
  o1[0] = a01 * scale; o1[1] = a11 * scale;
  o2[0] = a02 * scale; o2[1] = a12 * scale;
  o3[0] = a03 * scale; o3[1] = a13 * scale;
}

// Softmax over the (contiguous) s axis, in place. One block per (b,h) row.
__global__ __launch_bounds__(256) void k_sm(float* __restrict__ sc) {
  __shared__ float red[8];
  const int tid = threadIdx.x, w = tid >> 6, l = tid & 63;
  float* p = sc + (size_t)blockIdx.x * SLEN;
  float4 x = reinterpret_cast<const float4*>(p)[tid];
  float mx = fmaxf(fmaxf(x.x, x.y), fmaxf(x.z, x.w));
#pragma unroll
  for (int off = 32; off; off >>= 1) mx = fmaxf(mx, __shfl_xor(mx, off, 64));
  if (l == 0) red[w] = mx;
  __syncthreads();
  mx = fmaxf(fmaxf(red[0], red[1]), fmaxf(red[2], red[3]));
  float4 e;
  e.x = __expf(x.x - mx); e.y = __expf(x.y - mx);
  e.z = __expf(x.z - mx); e.w = __expf(x.w - mx);
  float sum = e.x + e.y + e.z + e.w;
  sum = wred_sum(sum);
  if (l == 0) red[4 + w] = sum;
  __syncthreads();
  sum = red[4] + red[5] + red[6] + red[7];
  const float inv = 1.f / sum;
  e.x *= inv; e.y *= inv; e.z *= inv; e.w *= inv;
  reinterpret_cast<float4*>(p)[tid] = e;
}

// K3: partial c[ch][b][h][m] = sum_{s in chunk} attn[b][h][s] * values[s][b][m].
// Block = (b, s-chunk). Threads parallel over m (coalesced values), attn chunk in LDS.
template <int NCH>
__global__ __launch_bounds__(256) void k3_cpart(const float* __restrict__ values,
                                                const float* __restrict__ attn,
                                                float* __restrict__ cp) {
  constexpr int SC = SLEN / NCH;
  __shared__ __align__(16) float al[NH * SC];
  const int b = blockIdx.x & 63;
  const int ch = blockIdx.x >> 6;
  const int s0 = ch * SC;
  const int tid = threadIdx.x;
  for (int f = tid; f < NH * SC / 4; f += 256) {
    int hh = f / (SC / 4), c4 = f % (SC / 4);
    *reinterpret_cast<float4*>(&al[hh * SC + c4 * 4]) =
        *reinterpret_cast<const float4*>(attn + ((size_t)b * NH + hh) * SLEN + s0 + c4 * 4);
  }
  __syncthreads();
  const int m4 = tid * 4;
  float4 acc[NH];
#pragma unroll
  for (int i = 0; i < NH; ++i) acc[i] = make_float4(0.f, 0.f, 0.f, 0.f);
  const float* vbase = values + ((size_t)s0 * NB + b) * DMODEL + m4;
  for (int sl = 0; sl < SC; sl += 4) {
    const float* vp = vbase + (size_t)sl * NB * DMODEL;
    float4 v0 = *reinterpret_cast<const float4*>(vp);
    float4 v1 = *reinterpret_cast<const float4*>(vp + (size_t)1 * NB * DMODEL);
    float4 v2 = *reinterpret_cast<const float4*>(vp + (size_t)2 * NB * DMODEL);
    float4 v3 = *reinterpret_cast<const float4*>(vp + (size_t)3 * NB * DMODEL);
#pragma unroll
    for (int hh = 0; hh < NH; ++hh) {
      float4 a = *reinterpret_cast<const float4*>(&al[hh * SC + sl]);
      FMA4_BCAST(acc[hh], a, v0, v1, v2, v3);
    }
  }
#pragma unroll
  for (int hh = 0; hh < NH; ++hh)
    *reinterpret_cast<float4*>(cp + (((size_t)ch * NB + b) * NH + hh) * DMODEL + m4) = acc[hh];
}

// K4: out[b][h*64+d] = sum_m Wk[h*64+d][m] * (sum_ch cp[ch][b][h][m]).
// Block = (h, 4 b's): c summed into LDS once, then wave-per-16-d dot products
// with coalesced Wk rows + full-wave shuffle reduction.
template <int NCH>
__global__ __launch_bounds__(256) void k4_out(const float* __restrict__ cp,
                                              const float* __restrict__ Wk,
                                              float* __restrict__ out) {
  __shared__ __align__(16) float cl[4 * DMODEL];
  const int h = blockIdx.x & 15;
  const int b0 = (blockIdx.x >> 4) * 4;
  const int tid = threadIdx.x, w = tid >> 6, l = tid & 63;
  for (int f = tid; f < 4 * DMODEL / 4; f += 256) {
    int bi = f >> 8, m4 = (f & 255) * 4;
    float4 s = make_float4(0.f, 0.f, 0.f, 0.f);
#pragma unroll
    for (int ch = 0; ch < NCH; ++ch) {
      float4 t = *reinterpret_cast<const float4*>(
          cp + (((size_t)ch * NB + b0 + bi) * NH + h) * DMODEL + m4);
      s.x += t.x; s.y += t.y; s.z += t.z; s.w += t.w;
    }
    *reinterpret_cast<float4*>(&cl[bi * DMODEL + m4]) = s;
  }
  __syncthreads();
  float4 c[4][4];
#pragma unroll
  for (int bi = 0; bi < 4; ++bi)
#pragma unroll
    for (int k = 0; k < 4; ++k)
      c[bi][k] = *reinterpret_cast<const float4*>(&cl[bi * DMODEL + l * 16 + k * 4]);
  for (int jj = 0; jj < 16; ++jj) {
    const int d = w * 16 + jj;
    const float4* wr = reinterpret_cast<const float4*>(Wk + (size_t)(h * HD + d) * DMODEL) + l * 4;
    const float4 w0 = wr[0], w1 = wr[1], w2 = wr[2], w3 = wr[3];
#pragma unroll
    for (int bi = 0; bi < 4; ++bi) {
      float s = 0.f;
      DOT4_ACC(s, w0, c[bi][0]); DOT4_ACC(s, w1, c[bi][1]);
      DOT4_ACC(s, w2, c[bi][2]); DOT4_ACC(s, w3, c[bi][3]);
      s = wred_sum(s);
      if (l == 0) out[(size_t)(b0 + bi) * (NH * HD) + h * HD + d] = s;
    }
  }
}

extern "C" void kernel_launch(void* const* d_in, const int* in_sizes, int n_in,
                              void* d_out, int out_size, void* d_ws, size_t ws_size,
                              hipStream_t stream) {
  const float* query  = (const float*)d_in[0];
  const float* keys   = (const float*)d_in[1];
  const float* values = (const float*)d_in[2];
  const float* Wq     = (const float*)d_in[3];
  const float* Wk     = (const float*)d_in[4];
  float* out = (float*)d_out;

  float* W  = (float*)d_ws;
  float* qp = W;                                   // 64*1024
  float* qt = qp + (size_t)NB * DMODEL;            // 64*16*1024
  float* sc = qt + (size_t)NB * NH * DMODEL;       // 64*16*1024 (scores -> attn in place)
  float* cp = sc + (size_t)NB * NH * SLEN;         // NCH*64*16*1024

  const size_t base_floats = (size_t)NB * DMODEL + 2 * (size_t)NB * NH * DMODEL;

  k0_qp<<<256, 256, 0, stream>>>(query, Wq, qp);
  k1_qt<<<128, 256, 0, stream>>>(qp, Wk, qt);
  k2_scores<<<512, 256, 0, stream>>>(keys, qt, sc);
  k_sm<<<NB * NH, 256, 0, stream>>>(sc);

  const size_t chunk_floats = (size_t)NB * NH * DMODEL;
  if (ws_size >= (base_floats + 8 * chunk_floats) * sizeof(float)) {
    k3_cpart<8><<<8 * NB, 256, 0, stream>>>(values, sc, cp);
    k4_out<8><<<NH * (NB / 4), 256, 0, stream>>>(cp, Wk, out);
  } else if (ws_size >= (base_floats + 4 * chunk_floats) * sizeof(float)) {
    k3_cpart<4><<<4 * NB, 256, 0, stream>>>(values, sc, cp);
    k4_out<4><<<NH * (NB / 4), 256, 0, stream>>>(cp, Wk, out);
  } else {
    k3_cpart<2><<<2 * NB, 256, 0, stream>>>(values, sc, cp);
    k4_out<2><<<NH * (NB / 4), 256, 0, stream>>>(cp, Wk, out);
  }
}

// Round 3
// 299.689 us; speedup vs baseline: 1.3983x; 1.3983x over previous
//
#include <hip/hip_runtime.h>
#include <cstddef>
#include <cstdint>

#define NH 16
#define HD 64
#define SLEN 1024
#define NB 64
#define DMODEL 1024

#define DOT4_ACC(acc, k, q) \
  acc = fmaf((k).x, (q).x, fmaf((k).y, (q).y, fmaf((k).z, (q).z, fmaf((k).w, (q).w, (acc)))))

#define FMA4_BCAST(accv, qv, w0_, w1_, w2_, w3_) do { \
  (accv).x = fmaf((qv).x, (w0_).x, fmaf((qv).y, (w1_).x, fmaf((qv).z, (w2_).x, fmaf((qv).w, (w3_).x, (accv).x)))); \
  (accv).y = fmaf((qv).x, (w0_).y, fmaf((qv).y, (w1_).y, fmaf((qv).z, (w2_).y, fmaf((qv).w, (w3_).y, (accv).y)))); \
  (accv).z = fmaf((qv).x, (w0_).z, fmaf((qv).y, (w1_).z, fmaf((qv).z, (w2_).z, fmaf((qv).w, (w3_).z, (accv).z)))); \
  (accv).w = fmaf((qv).x, (w0_).w, fmaf((qv).y, (w1_).w, fmaf((qv).z, (w2_).w, fmaf((qv).w, (w3_).w, (accv).w)))); \
} while (0)

__device__ __forceinline__ float wred_sum(float v) {
#pragma unroll
  for (int off = 32; off; off >>= 1) v += __shfl_xor(v, off, 64);
  return v;
}

// K0: qp[b][j] = sum_c query[b][c] * Wq[j][c].  One wave per j, Wq row in regs,
// loop b with full-wave shuffle reduction.
__global__ __launch_bounds__(256) void k0_qp(const float* __restrict__ query,
                                             const float* __restrict__ Wq,
                                             float* __restrict__ qp) {
  const int tid = threadIdx.x;
  const int w = tid >> 6, l = tid & 63;
  const int j = blockIdx.x * 4 + w;  // 0..1023
  const float4* wr = reinterpret_cast<const float4*>(Wq + (size_t)j * DMODEL) + l * 4;
  const float4 w0 = wr[0], w1 = wr[1], w2 = wr[2], w3 = wr[3];
  for (int b = 0; b < NB; ++b) {
    const float4* qr = reinterpret_cast<const float4*>(query + (size_t)b * DMODEL) + l * 4;
    float4 q0 = qr[0], q1 = qr[1], q2 = qr[2], q3 = qr[3];
    float s = 0.f;
    DOT4_ACC(s, w0, q0); DOT4_ACC(s, w1, q1); DOT4_ACC(s, w2, q2); DOT4_ACC(s, w3, q3);
    s = wred_sum(s);
    if (l == 0) qp[(size_t)b * DMODEL + j] = s;
  }
}

// K1: qt[b][h][m] = sum_d qp[b][h*64+d] * Wk[h*64+d][m].
// Block = (h, 8 b's). Threads parallel over m (coalesced Wk rows), qp broadcast from LDS.
__global__ __launch_bounds__(256) void k1_qt(const float* __restrict__ qp,
                                             const float* __restrict__ Wk,
                                             float* __restrict__ qt) {
  __shared__ __align__(16) float qpl[8][HD];
  const int h = blockIdx.x & 15;
  const int b0 = (blockIdx.x >> 4) * 8;
  const int tid = threadIdx.x;
  for (int f = tid; f < 8 * HD; f += 256) {
    int bi = f >> 6, d = f & 63;
    qpl[bi][d] = qp[(size_t)(b0 + bi) * DMODEL + h * HD + d];
  }
  __syncthreads();
  const int m4 = tid * 4;
  float4 acc[8];
#pragma unroll
  for (int i = 0; i < 8; ++i) acc[i] = make_float4(0.f, 0.f, 0.f, 0.f);
  const float* wbase = Wk + (size_t)(h * HD) * DMODEL + m4;
  for (int d = 0; d < HD; d += 4) {
    float4 wk0 = *reinterpret_cast<const float4*>(wbase + (size_t)(d + 0) * DMODEL);
    float4 wk1 = *reinterpret_cast<const float4*>(wbase + (size_t)(d + 1) * DMODEL);
    float4 wk2 = *reinterpret_cast<const float4*>(wbase + (size_t)(d + 2) * DMODEL);
    float4 wk3 = *reinterpret_cast<const float4*>(wbase + (size_t)(d + 3) * DMODEL);
#pragma unroll
    for (int bi = 0; bi < 8; ++bi) {
      float4 q = *reinterpret_cast<const float4*>(&qpl[bi][d]);
      FMA4_BCAST(acc[bi], q, wk0, wk1, wk2, wk3);
    }
  }
#pragma unroll
  for (int bi = 0; bi < 8; ++bi)
    *reinterpret_cast<float4*>(qt + ((size_t)(b0 + bi) * NH + h) * DMODEL + m4) = acc[bi];
}

// K2: sc[b][h][s] = (1/8) * sum_m qt[b][h][m] * keys[s][b][m].
// Block = (b, 64-s tile); wave w owns h-quad w*4..w*4+3; lane bits [1:0] = hg are an
// M-STRIPE (4 lanes cover one contiguous 64B line of the key row -> fully-consumed
// transactions), lane bits [5:2] = sg cover 2 s each. Partial dots per stripe are
// folded with shfl_xor(1,2). Streams keys exactly once, coalesced. Grid 1024 (4/CU).
__global__ __launch_bounds__(256) void k2_scores(const float* __restrict__ keys,
                                                 const float* __restrict__ qt,
                                                 float* __restrict__ sc) {
  const int b  = blockIdx.x & 63;
  const int st = blockIdx.x >> 6;          // 0..15
  const int tid = threadIdx.x, w = tid >> 6, l = tid & 63;
  const int hg = l & 3;                    // m-stripe index
  const int sg = l >> 2;                   // 0..15
  const int hq = w * 4;                    // wave's h-quad base
  const float* qb0 = qt + ((size_t)b * NH + hq) * DMODEL + hg * 4;
  const float* qb1 = qb0 + DMODEL;
  const float* qb2 = qb0 + 2 * DMODEL;
  const float* qb3 = qb0 + 3 * DMODEL;
  const float scale = 0.125f;  // 1/sqrt(64)
  for (int sp = 0; sp < 2; ++sp) {
    const int s0 = st * 64 + sp * 32 + sg * 2;
    const float* k0p = keys + ((size_t)s0 * NB + b) * DMODEL + hg * 4;
    const float* k1p = k0p + (size_t)NB * DMODEL;
    float s00 = 0.f, s01 = 0.f, s10 = 0.f, s11 = 0.f;
    float s20 = 0.f, s21 = 0.f, s30 = 0.f, s31 = 0.f;
#pragma unroll 4
    for (int m = 0; m < DMODEL; m += 16) {
      float4 ka = *reinterpret_cast<const float4*>(k0p + m);
      float4 kb = *reinterpret_cast<const float4*>(k1p + m);
      float4 q0 = *reinterpret_cast<const float4*>(qb0 + m);
      float4 q1 = *reinterpret_cast<const float4*>(qb1 + m);
      float4 q2 = *reinterpret_cast<const float4*>(qb2 + m);
      float4 q3 = *reinterpret_cast<const float4*>(qb3 + m);
      DOT4_ACC(s00, ka, q0); DOT4_ACC(s01, kb, q0);
      DOT4_ACC(s10, ka, q1); DOT4_ACC(s11, kb, q1);
      DOT4_ACC(s20, ka, q2); DOT4_ACC(s21, kb, q2);
      DOT4_ACC(s30, ka, q3); DOT4_ACC(s31, kb, q3);
    }
#define RED2(x) do { x += __shfl_xor(x, 1, 64); x += __shfl_xor(x, 2, 64); } while (0)
    RED2(s00); RED2(s01); RED2(s10); RED2(s11);
    RED2(s20); RED2(s21); RED2(s30); RED2(s31);
#undef RED2
    // lane hg writes head hq+hg (static selection -> no scratch)
    float r0 = hg == 0 ? s00 : hg == 1 ? s10 : hg == 2 ? s20 : s30;
    float r1 = hg == 0 ? s01 : hg == 1 ? s11 : hg == 2 ? s21 : s31;
    float* o = sc + ((size_t)b * NH + hq + hg) * SLEN + s0;
    o[0] = r0 * scale;
    o[1] = r1 * scale;
  }
}

// Softmax over the (contiguous) s axis, in place. One block per (b,h) row.
__global__ __launch_bounds__(256) void k_sm(float* __restrict__ sc) {
  __shared__ float red[8];
  const int tid = threadIdx.x, w = tid >> 6, l = tid & 63;
  float* p = sc + (size_t)blockIdx.x * SLEN;
  float4 x = reinterpret_cast<const float4*>(p)[tid];
  float mx = fmaxf(fmaxf(x.x, x.y), fmaxf(x.z, x.w));
#pragma unroll
  for (int off = 32; off; off >>= 1) mx = fmaxf(mx, __shfl_xor(mx, off, 64));
  if (l == 0) red[w] = mx;
  __syncthreads();
  mx = fmaxf(fmaxf(red[0], red[1]), fmaxf(red[2], red[3]));
  float4 e;
  e.x = __expf(x.x - mx); e.y = __expf(x.y - mx);
  e.z = __expf(x.z - mx); e.w = __expf(x.w - mx);
  float sum = e.x + e.y + e.z + e.w;
  sum = wred_sum(sum);
  if (l == 0) red[4 + w] = sum;
  __syncthreads();
  sum = red[4] + red[5] + red[6] + red[7];
  const float inv = 1.f / sum;
  e.x *= inv; e.y *= inv; e.z *= inv; e.w *= inv;
  reinterpret_cast<float4*>(p)[tid] = e;
}

// K3: partial c[ch][b][h][m] = sum_{s in chunk} attn[b][h][s] * values[s][b][m].
// Block = (b, s-chunk). Threads parallel over m (coalesced values), attn chunk in LDS.
template <int NCH>
__global__ __launch_bounds__(256) void k3_cpart(const float* __restrict__ values,
                                                const float* __restrict__ attn,
                                                float* __restrict__ cp) {
  constexpr int SC = SLEN / NCH;
  __shared__ __align__(16) float al[NH * SC];
  const int b = blockIdx.x & 63;
  const int ch = blockIdx.x >> 6;
  const int s0 = ch * SC;
  const int tid = threadIdx.x;
  for (int f = tid; f < NH * SC / 4; f += 256) {
    int hh = f / (SC / 4), c4 = f % (SC / 4);
    *reinterpret_cast<float4*>(&al[hh * SC + c4 * 4]) =
        *reinterpret_cast<const float4*>(attn + ((size_t)b * NH + hh) * SLEN + s0 + c4 * 4);
  }
  __syncthreads();
  const int m4 = tid * 4;
  float4 acc[NH];
#pragma unroll
  for (int i = 0; i < NH; ++i) acc[i] = make_float4(0.f, 0.f, 0.f, 0.f);
  const float* vbase = values + ((size_t)s0 * NB + b) * DMODEL + m4;
  for (int sl = 0; sl < SC; sl += 4) {
    const float* vp = vbase + (size_t)sl * NB * DMODEL;
    float4 v0 = *reinterpret_cast<const float4*>(vp);
    float4 v1 = *reinterpret_cast<const float4*>(vp + (size_t)1 * NB * DMODEL);
    float4 v2 = *reinterpret_cast<const float4*>(vp + (size_t)2 * NB * DMODEL);
    float4 v3 = *reinterpret_cast<const float4*>(vp + (size_t)3 * NB * DMODEL);
#pragma unroll
    for (int hh = 0; hh < NH; ++hh) {
      float4 a = *reinterpret_cast<const float4*>(&al[hh * SC + sl]);
      FMA4_BCAST(acc[hh], a, v0, v1, v2, v3);
    }
  }
#pragma unroll
  for (int hh = 0; hh < NH; ++hh)
    *reinterpret_cast<float4*>(cp + (((size_t)ch * NB + b) * NH + hh) * DMODEL + m4) = acc[hh];
}

// K4: out[b][h*64+d] = sum_m Wk[h*64+d][m] * (sum_ch cp[ch][b][h][m]).
// Block = (h, 4 b's): c summed into LDS once, then wave-per-16-d dot products
// with coalesced Wk rows + full-wave shuffle reduction.
template <int NCH>
__global__ __launch_bounds__(256) void k4_out(const float* __restrict__ cp,
                                              const float* __restrict__ Wk,
                                              float* __restrict__ out) {
  __shared__ __align__(16) float cl[4 * DMODEL];
  const int h = blockIdx.x & 15;
  const int b0 = (blockIdx.x >> 4) * 4;
  const int tid = threadIdx.x, w = tid >> 6, l = tid & 63;
  for (int f = tid; f < 4 * DMODEL / 4; f += 256) {
    int bi = f >> 8, m4 = (f & 255) * 4;
    float4 s = make_float4(0.f, 0.f, 0.f, 0.f);
#pragma unroll
    for (int ch = 0; ch < NCH; ++ch) {
      float4 t = *reinterpret_cast<const float4*>(
          cp + (((size_t)ch * NB + b0 + bi) * NH + h) * DMODEL + m4);
      s.x += t.x; s.y += t.y; s.z += t.z; s.w += t.w;
    }
    *reinterpret_cast<float4*>(&cl[bi * DMODEL + m4]) = s;
  }
  __syncthreads();
  float4 c[4][4];
#pragma unroll
  for (int bi = 0; bi < 4; ++bi)
#pragma unroll
    for (int k = 0; k < 4; ++k)
      c[bi][k] = *reinterpret_cast<const float4*>(&cl[bi * DMODEL + l * 16 + k * 4]);
  for (int jj = 0; jj < 16; ++jj) {
    const int d = w * 16 + jj;
    const float4* wr = reinterpret_cast<const float4*>(Wk + (size_t)(h * HD + d) * DMODEL) + l * 4;
    const float4 w0 = wr[0], w1 = wr[1], w2 = wr[2], w3 = wr[3];
#pragma unroll
    for (int bi = 0; bi < 4; ++bi) {
      float s = 0.f;
      DOT4_ACC(s, w0, c[bi][0]); DOT4_ACC(s, w1, c[bi][1]);
      DOT4_ACC(s, w2, c[bi][2]); DOT4_ACC(s, w3, c[bi][3]);
      s = wred_sum(s);
      if (l == 0) out[(size_t)(b0 + bi) * (NH * HD) + h * HD + d] = s;
    }
  }
}

extern "C" void kernel_launch(void* const* d_in, const int* in_sizes, int n_in,
                              void* d_out, int out_size, void* d_ws, size_t ws_size,
                              hipStream_t stream) {
  const float* query  = (const float*)d_in[0];
  const float* keys   = (const float*)d_in[1];
  const float* values = (const float*)d_in[2];
  const float* Wq     = (const float*)d_in[3];
  const float* Wk     = (const float*)d_in[4];
  float* out = (float*)d_out;

  float* W  = (float*)d_ws;
  float* qp = W;                                   // 64*1024
  float* qt = qp + (size_t)NB * DMODEL;            // 64*16*1024
  float* sc = qt + (size_t)NB * NH * DMODEL;       // 64*16*1024 (scores -> attn in place)
  float* cp = sc + (size_t)NB * NH * SLEN;         // NCH*64*16*1024

  const size_t base_floats = (size_t)NB * DMODEL + 2 * (size_t)NB * NH * DMODEL;

  k0_qp<<<256, 256, 0, stream>>>(query, Wq, qp);
  k1_qt<<<128, 256, 0, stream>>>(qp, Wk, qt);
  k2_scores<<<1024, 256, 0, stream>>>(keys, qt, sc);
  k_sm<<<NB * NH, 256, 0, stream>>>(sc);

  const size_t chunk_floats = (size_t)NB * NH * DMODEL;
  if (ws_size >= (base_floats + 16 * chunk_floats) * sizeof(float)) {
    k3_cpart<16><<<16 * NB, 256, 0, stream>>>(values, sc, cp);
    k4_out<16><<<NH * (NB / 4), 256, 0, stream>>>(cp, Wk, out);
  } else if (ws_size >= (base_floats + 8 * chunk_floats) * sizeof(float)) {
    k3_cpart<8><<<8 * NB, 256, 0, stream>>>(values, sc, cp);
    k4_out<8><<<NH * (NB / 4), 256, 0, stream>>>(cp, Wk, out);
  } else if (ws_size >= (base_floats + 4 * chunk_floats) * sizeof(float)) {
    k3_cpart<4><<<4 * NB, 256, 0, stream>>>(values, sc, cp);
    k4_out<4><<<NH * (NB / 4), 256, 0, stream>>>(cp, Wk, out);
  } else {
    k3_cpart<2><<<2 * NB, 256, 0, stream>>>(values, sc, cp);
    k4_out<2><<<NH * (NB / 4), 256, 0, stream>>>(cp, Wk, out);
  }
}

// Round 4
// 255.326 us; speedup vs baseline: 1.6413x; 1.1738x over previous
//
#include <hip/hip_runtime.h>
#include <cstddef>
#include <cstdint>

#define NH 16
#define HD 64
#define SLEN 1024
#define NB 64
#define DMODEL 1024

#define DOT4_ACC(acc, k, q) \
  acc = fmaf((k).x, (q).x, fmaf((k).y, (q).y, fmaf((k).z, (q).z, fmaf((k).w, (q).w, (acc)))))

#define FMA4_BCAST(accv, qv, w0_, w1_, w2_, w3_) do { \
  (accv).x = fmaf((qv).x, (w0_).x, fmaf((qv).y, (w1_).x, fmaf((qv).z, (w2_).x, fmaf((qv).w, (w3_).x, (accv).x)))); \
  (accv).y = fmaf((qv).x, (w0_).y, fmaf((qv).y, (w1_).y, fmaf((qv).z, (w2_).y, fmaf((qv).w, (w3_).y, (accv).y)))); \
  (accv).z = fmaf((qv).x, (w0_).z, fmaf((qv).y, (w1_).z, fmaf((qv).z, (w2_).z, fmaf((qv).w, (w3_).z, (accv).z)))); \
  (accv).w = fmaf((qv).x, (w0_).w, fmaf((qv).y, (w1_).w, fmaf((qv).z, (w2_).w, fmaf((qv).w, (w3_).w, (accv).w)))); \
} while (0)

__device__ __forceinline__ float wred_sum(float v) {
#pragma unroll
  for (int off = 32; off; off >>= 1) v += __shfl_xor(v, off, 64);
  return v;
}

// K0: qp[b][j] = sum_c query[b][c] * Wq[j][c].
__global__ __launch_bounds__(256) void k0_qp(const float* __restrict__ query,
                                             const float* __restrict__ Wq,
                                             float* __restrict__ qp) {
  const int tid = threadIdx.x;
  const int w = tid >> 6, l = tid & 63;
  const int j = blockIdx.x * 4 + w;  // 0..1023
  const float4* wr = reinterpret_cast<const float4*>(Wq + (size_t)j * DMODEL) + l * 4;
  const float4 w0 = wr[0], w1 = wr[1], w2 = wr[2], w3 = wr[3];
  for (int b = 0; b < NB; ++b) {
    const float4* qr = reinterpret_cast<const float4*>(query + (size_t)b * DMODEL) + l * 4;
    float4 q0 = qr[0], q1 = qr[1], q2 = qr[2], q3 = qr[3];
    float s = 0.f;
    DOT4_ACC(s, w0, q0); DOT4_ACC(s, w1, q1); DOT4_ACC(s, w2, q2); DOT4_ACC(s, w3, q3);
    s = wred_sum(s);
    if (l == 0) qp[(size_t)b * DMODEL + j] = s;
  }
}

// K1: qt[b][h][m] = sum_d qp[b][h*64+d] * Wk[h*64+d][m].
__global__ __launch_bounds__(256) void k1_qt(const float* __restrict__ qp,
                                             const float* __restrict__ Wk,
                                             float* __restrict__ qt) {
  __shared__ __align__(16) float qpl[8][HD];
  const int h = blockIdx.x & 15;
  const int b0 = (blockIdx.x >> 4) * 8;
  const int tid = threadIdx.x;
  for (int f = tid; f < 8 * HD; f += 256) {
    int bi = f >> 6, d = f & 63;
    qpl[bi][d] = qp[(size_t)(b0 + bi) * DMODEL + h * HD + d];
  }
  __syncthreads();
  const int m4 = tid * 4;
  float4 acc[8];
#pragma unroll
  for (int i = 0; i < 8; ++i) acc[i] = make_float4(0.f, 0.f, 0.f, 0.f);
  const float* wbase = Wk + (size_t)(h * HD) * DMODEL + m4;
  for (int d = 0; d < HD; d += 4) {
    float4 wk0 = *reinterpret_cast<const float4*>(wbase + (size_t)(d + 0) * DMODEL);
    float4 wk1 = *reinterpret_cast<const float4*>(wbase + (size_t)(d + 1) * DMODEL);
    float4 wk2 = *reinterpret_cast<const float4*>(wbase + (size_t)(d + 2) * DMODEL);
    float4 wk3 = *reinterpret_cast<const float4*>(wbase + (size_t)(d + 3) * DMODEL);
#pragma unroll
    for (int bi = 0; bi < 8; ++bi) {
      float4 q = *reinterpret_cast<const float4*>(&qpl[bi][d]);
      FMA4_BCAST(acc[bi], q, wk0, wk1, wk2, wk3);
    }
  }
#pragma unroll
  for (int bi = 0; bi < 8; ++bi)
    *reinterpret_cast<float4*>(qt + ((size_t)(b0 + bi) * NH + h) * DMODEL + m4) = acc[bi];
}

// K2 v3: sc[b][h][s] = (1/8) * sum_m qt[b][h][m] * keys[s][b][m].
// Block = 128 thr (2 waves) = (b, st) covering 64 s. All 16 qt rows staged in LDS
// (two 512-m phases, 32 KB). Lane: hg = m-stripe (quad covers one 64B key line),
// sg+si = 2 s per lane. Each key float4 feeds 16 head-FMAs (4x intensity of v2).
// Grid 1024 -> 4 blocks/CU, 8 waves/CU, LDS 128 KB/CU.
__global__ __launch_bounds__(128) void k2_scores(const float* __restrict__ keys,
                                                 const float* __restrict__ qt,
                                                 float* __restrict__ sc) {
  __shared__ __align__(16) float ql[NH][512];  // 32 KB
  const int b  = blockIdx.x & 63;
  const int st = blockIdx.x >> 6;          // 0..15
  const int tid = threadIdx.x, w = tid >> 6, l = tid & 63;
  const int hg = l & 3;                    // m-stripe in quad
  const int sg = l >> 2;                   // 0..15
  const int s_a = st * 64 + w * 32 + sg;   // lane's 2 s values
  const int s_b = s_a + 16;
  const float* ka = keys + ((size_t)s_a * NB + b) * DMODEL + hg * 4;
  const float* kb = keys + ((size_t)s_b * NB + b) * DMODEL + hg * 4;
  float acc0[NH], acc1[NH];
#pragma unroll
  for (int hh = 0; hh < NH; ++hh) { acc0[hh] = 0.f; acc1[hh] = 0.f; }

  for (int ph = 0; ph < 2; ++ph) {
    __syncthreads();  // protect previous phase's reads before overwrite
    // stage qt[b][0..15][ph*512 .. ph*512+512) -> ql  (2048 float4, 128 thr)
    for (int f = tid; f < 2048; f += 128) {
      int hh = f >> 7, m4 = (f & 127) * 4;
      *reinterpret_cast<float4*>(&ql[hh][m4]) = *reinterpret_cast<const float4*>(
          qt + ((size_t)b * NH + hh) * DMODEL + ph * 512 + m4);
    }
    __syncthreads();
    const float* kpa = ka + ph * 512;
    const float* kpb = kb + ph * 512;
#pragma unroll 4
    for (int m = 0; m < 512; m += 16) {
      float4 k0 = *reinterpret_cast<const float4*>(kpa + m);
      float4 k1 = *reinterpret_cast<const float4*>(kpb + m);
#pragma unroll
      for (int hh = 0; hh < NH; ++hh) {
        float4 q = *reinterpret_cast<const float4*>(&ql[hh][m + hg * 4]);
        DOT4_ACC(acc0[hh], k0, q);
        DOT4_ACC(acc1[hh], k1, q);
      }
    }
  }
  // fold the 4 m-stripes within each lane-quad
#pragma unroll
  for (int hh = 0; hh < NH; ++hh) {
    acc0[hh] += __shfl_xor(acc0[hh], 1, 64); acc0[hh] += __shfl_xor(acc0[hh], 2, 64);
    acc1[hh] += __shfl_xor(acc1[hh], 1, 64); acc1[hh] += __shfl_xor(acc1[hh], 2, 64);
  }
  const float scale = 0.125f;  // 1/sqrt(64)
  // lane hg writes heads hg*4..hg*4+3 (static selection, no scratch)
#pragma unroll
  for (int j = 0; j < 4; ++j) {
    float r0 = hg == 0 ? acc0[j] : hg == 1 ? acc0[4 + j] : hg == 2 ? acc0[8 + j] : acc0[12 + j];
    float r1 = hg == 0 ? acc1[j] : hg == 1 ? acc1[4 + j] : hg == 2 ? acc1[8 + j] : acc1[12 + j];
    float* o = sc + ((size_t)b * NH + hg * 4 + j) * SLEN;
    o[s_a] = r0 * scale;
    o[s_b] = r1 * scale;
  }
}

// Softmax over the (contiguous) s axis, in place. One block per (b,h) row.
__global__ __launch_bounds__(256) void k_sm(float* __restrict__ sc) {
  __shared__ float red[8];
  const int tid = threadIdx.x, w = tid >> 6, l = tid & 63;
  float* p = sc + (size_t)blockIdx.x * SLEN;
  float4 x = reinterpret_cast<const float4*>(p)[tid];
  float mx = fmaxf(fmaxf(x.x, x.y), fmaxf(x.z, x.w));
#pragma unroll
  for (int off = 32; off; off >>= 1) mx = fmaxf(mx, __shfl_xor(mx, off, 64));
  if (l == 0) red[w] = mx;
  __syncthreads();
  mx = fmaxf(fmaxf(red[0], red[1]), fmaxf(red[2], red[3]));
  float4 e;
  e.x = __expf(x.x - mx); e.y = __expf(x.y - mx);
  e.z = __expf(x.z - mx); e.w = __expf(x.w - mx);
  float sum = e.x + e.y + e.z + e.w;
  sum = wred_sum(sum);
  if (l == 0) red[4 + w] = sum;
  __syncthreads();
  sum = red[4] + red[5] + red[6] + red[7];
  const float inv = 1.f / sum;
  e.x *= inv; e.y *= inv; e.z *= inv; e.w *= inv;
  reinterpret_cast<float4*>(p)[tid] = e;
}

// K3: partial c[ch][b][h][m] = sum_{s in chunk} attn[b][h][s] * values[s][b][m].
// attn addresses are wave-uniform -> scalar loads (s_load) on the SMEM pipe;
// vector pipe streams values coalesced (256 thr x float4 = full row).
template <int NCH>
__global__ __launch_bounds__(256) void k3_cpart(const float* __restrict__ values,
                                                const float* __restrict__ attn,
                                                float* __restrict__ cp) {
  constexpr int SC = SLEN / NCH;
  const int b = blockIdx.x & 63;
  const int ch = blockIdx.x >> 6;
  const int s0 = ch * SC;
  const int tid = threadIdx.x;
  const int m4 = tid * 4;
  float4 acc[NH];
#pragma unroll
  for (int i = 0; i < NH; ++i) acc[i] = make_float4(0.f, 0.f, 0.f, 0.f);
  const float* vbase = values + ((size_t)s0 * NB + b) * DMODEL + m4;
  const float* abase = attn + (size_t)b * NH * SLEN + s0;
#pragma unroll 2
  for (int sl = 0; sl < SC; sl += 4) {
    const float* vp = vbase + (size_t)sl * NB * DMODEL;
    float4 v0 = *reinterpret_cast<const float4*>(vp);
    float4 v1 = *reinterpret_cast<const float4*>(vp + (size_t)1 * NB * DMODEL);
    float4 v2 = *reinterpret_cast<const float4*>(vp + (size_t)2 * NB * DMODEL);
    float4 v3 = *reinterpret_cast<const float4*>(vp + (size_t)3 * NB * DMODEL);
#pragma unroll
    for (int hh = 0; hh < NH; ++hh) {
      float4 a = *reinterpret_cast<const float4*>(abase + hh * SLEN + sl);  // uniform
      FMA4_BCAST(acc[hh], a, v0, v1, v2, v3);
    }
  }
#pragma unroll
  for (int hh = 0; hh < NH; ++hh)
    *reinterpret_cast<float4*>(cp + (((size_t)ch * NB + b) * NH + hh) * DMODEL + m4) = acc[hh];
}

// K4: out[b][h*64+d] = sum_m Wk[h*64+d][m] * (sum_ch cp[ch][b][h][m]).
template <int NCH>
__global__ __launch_bounds__(256) void k4_out(const float* __restrict__ cp,
                                              const float* __restrict__ Wk,
                                              float* __restrict__ out) {
  __shared__ __align__(16) float cl[4 * DMODEL];
  const int h = blockIdx.x & 15;
  const int b0 = (blockIdx.x >> 4) * 4;
  const int tid = threadIdx.x, w = tid >> 6, l = tid & 63;
  for (int f = tid; f < 4 * DMODEL / 4; f += 256) {
    int bi = f >> 8, m4 = (f & 255) * 4;
    float4 s = make_float4(0.f, 0.f, 0.f, 0.f);
#pragma unroll
    for (int ch = 0; ch < NCH; ++ch) {
      float4 t = *reinterpret_cast<const float4*>(
          cp + (((size_t)ch * NB + b0 + bi) * NH + h) * DMODEL + m4);
      s.x += t.x; s.y += t.y; s.z += t.z; s.w += t.w;
    }
    *reinterpret_cast<float4*>(&cl[bi * DMODEL + m4]) = s;
  }
  __syncthreads();
  float4 c[4][4];
#pragma unroll
  for (int bi = 0; bi < 4; ++bi)
#pragma unroll
    for (int k = 0; k < 4; ++k)
      c[bi][k] = *reinterpret_cast<const float4*>(&cl[bi * DMODEL + l * 16 + k * 4]);
  for (int jj = 0; jj < 16; ++jj) {
    const int d = w * 16 + jj;
    const float4* wr = reinterpret_cast<const float4*>(Wk + (size_t)(h * HD + d) * DMODEL) + l * 4;
    const float4 w0 = wr[0], w1 = wr[1], w2 = wr[2], w3 = wr[3];
#pragma unroll
    for (int bi = 0; bi < 4; ++bi) {
      float s = 0.f;
      DOT4_ACC(s, w0, c[bi][0]); DOT4_ACC(s, w1, c[bi][1]);
      DOT4_ACC(s, w2, c[bi][2]); DOT4_ACC(s, w3, c[bi][3]);
      s = wred_sum(s);
      if (l == 0) out[(size_t)(b0 + bi) * (NH * HD) + h * HD + d] = s;
    }
  }
}

extern "C" void kernel_launch(void* const* d_in, const int* in_sizes, int n_in,
                              void* d_out, int out_size, void* d_ws, size_t ws_size,
                              hipStream_t stream) {
  const float* query  = (const float*)d_in[0];
  const float* keys   = (const float*)d_in[1];
  const float* values = (const float*)d_in[2];
  const float* Wq     = (const float*)d_in[3];
  const float* Wk     = (const float*)d_in[4];
  float* out = (float*)d_out;

  float* W  = (float*)d_ws;
  float* qp = W;                                   // 64*1024
  float* qt = qp + (size_t)NB * DMODEL;            // 64*16*1024
  float* sc = qt + (size_t)NB * NH * DMODEL;       // 64*16*1024 (scores -> attn in place)
  float* cp = sc + (size_t)NB * NH * SLEN;         // NCH*64*16*1024

  const size_t base_floats = (size_t)NB * DMODEL + 2 * (size_t)NB * NH * DMODEL;

  k0_qp<<<256, 256, 0, stream>>>(query, Wq, qp);
  k1_qt<<<128, 256, 0, stream>>>(qp, Wk, qt);
  k2_scores<<<1024, 128, 0, stream>>>(keys, qt, sc);
  k_sm<<<NB * NH, 256, 0, stream>>>(sc);

  const size_t chunk_floats = (size_t)NB * NH * DMODEL;
  if (ws_size >= (base_floats + 16 * chunk_floats) * sizeof(float)) {
    k3_cpart<16><<<16 * NB, 256, 0, stream>>>(values, sc, cp);
    k4_out<16><<<NH * (NB / 4), 256, 0, stream>>>(cp, Wk, out);
  } else if (ws_size >= (base_floats + 8 * chunk_floats) * sizeof(float)) {
    k3_cpart<8><<<8 * NB, 256, 0, stream>>>(values, sc, cp);
    k4_out<8><<<NH * (NB / 4), 256, 0, stream>>>(cp, Wk, out);
  } else if (ws_size >= (base_floats + 4 * chunk_floats) * sizeof(float)) {
    k3_cpart<4><<<4 * NB, 256, 0, stream>>>(values, sc, cp);
    k4_out<4><<<NH * (NB / 4), 256, 0, stream>>>(cp, Wk, out);
  } else {
    k3_cpart<2><<<2 * NB, 256, 0, stream>>>(values, sc, cp);
    k4_out<2><<<NH * (NB / 4), 256, 0, stream>>>(cp, Wk, out);
  }
}

// Round 5
// 255.042 us; speedup vs baseline: 1.6431x; 1.0011x over previous
//
#include <hip/hip_runtime.h>
#include <cstddef>
#include <cstdint>

#define NH 16
#define HD 64
#define SLEN 1024
#define NB 64
#define DMODEL 1024

#define DOT4_ACC(acc, k, q) \
  acc = fmaf((k).x, (q).x, fmaf((k).y, (q).y, fmaf((k).z, (q).z, fmaf((k).w, (q).w, (acc)))))

#define FMA4_BCAST(accv, qv, w0_, w1_, w2_, w3_) do { \
  (accv).x = fmaf((qv).x, (w0_).x, fmaf((qv).y, (w1_).x, fmaf((qv).z, (w2_).x, fmaf((qv).w, (w3_).x, (accv).x)))); \
  (accv).y = fmaf((qv).x, (w0_).y, fmaf((qv).y, (w1_).y, fmaf((qv).z, (w2_).y, fmaf((qv).w, (w3_).y, (accv).y)))); \
  (accv).z = fmaf((qv).x, (w0_).z, fmaf((qv).y, (w1_).z, fmaf((qv).z, (w2_).z, fmaf((qv).w, (w3_).z, (accv).z)))); \
  (accv).w = fmaf((qv).x, (w0_).w, fmaf((qv).y, (w1_).w, fmaf((qv).z, (w2_).w, fmaf((qv).w, (w3_).w, (accv).w)))); \
} while (0)

__device__ __forceinline__ float wred_sum(float v) {
#pragma unroll
  for (int off = 32; off; off >>= 1) v += __shfl_xor(v, off, 64);
  return v;
}

// K0: qp[b][j] = sum_c query[b][c] * Wq[j][c].
__global__ __launch_bounds__(256) void k0_qp(const float* __restrict__ query,
                                             const float* __restrict__ Wq,
                                             float* __restrict__ qp) {
  const int tid = threadIdx.x;
  const int w = tid >> 6, l = tid & 63;
  const int j = blockIdx.x * 4 + w;  // 0..1023
  const float4* wr = reinterpret_cast<const float4*>(Wq + (size_t)j * DMODEL) + l * 4;
  const float4 w0 = wr[0], w1 = wr[1], w2 = wr[2], w3 = wr[3];
  for (int b = 0; b < NB; ++b) {
    const float4* qr = reinterpret_cast<const float4*>(query + (size_t)b * DMODEL) + l * 4;
    float4 q0 = qr[0], q1 = qr[1], q2 = qr[2], q3 = qr[3];
    float s = 0.f;
    DOT4_ACC(s, w0, q0); DOT4_ACC(s, w1, q1); DOT4_ACC(s, w2, q2); DOT4_ACC(s, w3, q3);
    s = wred_sum(s);
    if (l == 0) qp[(size_t)b * DMODEL + j] = s;
  }
}

// K1: qt[b][h][m] = sum_d qp[b][h*64+d] * Wk[h*64+d][m].
__global__ __launch_bounds__(256) void k1_qt(const float* __restrict__ qp,
                                             const float* __restrict__ Wk,
                                             float* __restrict__ qt) {
  __shared__ __align__(16) float qpl[8][HD];
  const int h = blockIdx.x & 15;
  const int b0 = (blockIdx.x >> 4) * 8;
  const int tid = threadIdx.x;
  for (int f = tid; f < 8 * HD; f += 256) {
    int bi = f >> 6, d = f & 63;
    qpl[bi][d] = qp[(size_t)(b0 + bi) * DMODEL + h * HD + d];
  }
  __syncthreads();
  const int m4 = tid * 4;
  float4 acc[8];
#pragma unroll
  for (int i = 0; i < 8; ++i) acc[i] = make_float4(0.f, 0.f, 0.f, 0.f);
  const float* wbase = Wk + (size_t)(h * HD) * DMODEL + m4;
  for (int d = 0; d < HD; d += 4) {
    float4 wk0 = *reinterpret_cast<const float4*>(wbase + (size_t)(d + 0) * DMODEL);
    float4 wk1 = *reinterpret_cast<const float4*>(wbase + (size_t)(d + 1) * DMODEL);
    float4 wk2 = *reinterpret_cast<const float4*>(wbase + (size_t)(d + 2) * DMODEL);
    float4 wk3 = *reinterpret_cast<const float4*>(wbase + (size_t)(d + 3) * DMODEL);
#pragma unroll
    for (int bi = 0; bi < 8; ++bi) {
      float4 q = *reinterpret_cast<const float4*>(&qpl[bi][d]);
      FMA4_BCAST(acc[bi], q, wk0, wk1, wk2, wk3);
    }
  }
#pragma unroll
  for (int bi = 0; bi < 8; ++bi)
    *reinterpret_cast<float4*>(qt + ((size_t)(b0 + bi) * NH + h) * DMODEL + m4) = acc[bi];
}

// K2 v5: partial scores over an m-half.
// scp[mh][b][h][s] = (1/8) * sum_{m in half} qt[b][h][m] * keys[s][b][m].
// Block = 128 thr = (b, st, mh). 16 qt rows x 512 m staged once in LDS (32 KB).
// Lane: hg = m-stripe within quad (quad covers one 64B key line), sg = s;
// 4 s-streams per lane (+0,+16,+32,+48) -> each LDS q read feeds 4 key streams.
// Grid 1024 -> 4 blk/CU, 8 waves/CU.
__global__ __launch_bounds__(128) void k2_scores(const float* __restrict__ keys,
                                                 const float* __restrict__ qt,
                                                 float* __restrict__ scp) {
  __shared__ __align__(16) float ql[NH][512];  // 32 KB
  const int b  = blockIdx.x & 63;
  const int st = (blockIdx.x >> 6) & 7;    // 0..7 (128-s tiles)
  const int mh = blockIdx.x >> 9;          // 0..1 (m-half)
  const int tid = threadIdx.x, w = tid >> 6, l = tid & 63;
  const int hg = l & 3;                    // m-stripe in quad
  const int sg = l >> 2;                   // 0..15
  for (int f = tid; f < 2048; f += 128) {
    int hh = f >> 7, m4 = (f & 127) * 4;
    *reinterpret_cast<float4*>(&ql[hh][m4]) = *reinterpret_cast<const float4*>(
        qt + ((size_t)b * NH + hh) * DMODEL + mh * 512 + m4);
  }
  __syncthreads();
  const int s_base = st * 128 + w * 64 + sg;  // + si*16, si=0..3
  const float* kp0 = keys + ((size_t)(s_base +  0) * NB + b) * DMODEL + mh * 512 + hg * 4;
  const float* kp1 = keys + ((size_t)(s_base + 16) * NB + b) * DMODEL + mh * 512 + hg * 4;
  const float* kp2 = keys + ((size_t)(s_base + 32) * NB + b) * DMODEL + mh * 512 + hg * 4;
  const float* kp3 = keys + ((size_t)(s_base + 48) * NB + b) * DMODEL + mh * 512 + hg * 4;
  float acc[4][NH];
#pragma unroll
  for (int si = 0; si < 4; ++si)
#pragma unroll
    for (int hh = 0; hh < NH; ++hh) acc[si][hh] = 0.f;
#pragma unroll 4
  for (int m = 0; m < 512; m += 16) {
    float4 k0 = *reinterpret_cast<const float4*>(kp0 + m);
    float4 k1 = *reinterpret_cast<const float4*>(kp1 + m);
    float4 k2 = *reinterpret_cast<const float4*>(kp2 + m);
    float4 k3 = *reinterpret_cast<const float4*>(kp3 + m);
#pragma unroll
    for (int hh = 0; hh < NH; ++hh) {
      float4 q = *reinterpret_cast<const float4*>(&ql[hh][m + hg * 4]);
      DOT4_ACC(acc[0][hh], k0, q);
      DOT4_ACC(acc[1][hh], k1, q);
      DOT4_ACC(acc[2][hh], k2, q);
      DOT4_ACC(acc[3][hh], k3, q);
    }
  }
#pragma unroll
  for (int si = 0; si < 4; ++si)
#pragma unroll
    for (int hh = 0; hh < NH; ++hh) {
      acc[si][hh] += __shfl_xor(acc[si][hh], 1, 64);
      acc[si][hh] += __shfl_xor(acc[si][hh], 2, 64);
    }
  const float scale = 0.125f;  // 1/sqrt(64); linear -> distributes over m-halves
  float* plane = scp + (size_t)mh * NB * NH * SLEN;
#pragma unroll
  for (int j = 0; j < 4; ++j) {
    float* o = plane + ((size_t)b * NH + hg * 4 + j) * SLEN + s_base;
#pragma unroll
    for (int si = 0; si < 4; ++si) {
      float r = hg == 0 ? acc[si][j] : hg == 1 ? acc[si][4 + j]
              : hg == 2 ? acc[si][8 + j] : acc[si][12 + j];
      o[si * 16] = r * scale;
    }
  }
}

// Softmax over s: sums the two partial-score planes, softmax, writes plane0.
__global__ __launch_bounds__(256) void k_sm(float* __restrict__ sc0,
                                            const float* __restrict__ sc1) {
  __shared__ float red[8];
  const int tid = threadIdx.x, w = tid >> 6, l = tid & 63;
  float* p0 = sc0 + (size_t)blockIdx.x * SLEN;
  const float* p1 = sc1 + (size_t)blockIdx.x * SLEN;
  float4 xa = reinterpret_cast<const float4*>(p0)[tid];
  float4 xb = reinterpret_cast<const float4*>(p1)[tid];
  float4 x = make_float4(xa.x + xb.x, xa.y + xb.y, xa.z + xb.z, xa.w + xb.w);
  float mx = fmaxf(fmaxf(x.x, x.y), fmaxf(x.z, x.w));
#pragma unroll
  for (int off = 32; off; off >>= 1) mx = fmaxf(mx, __shfl_xor(mx, off, 64));
  if (l == 0) red[w] = mx;
  __syncthreads();
  mx = fmaxf(fmaxf(red[0], red[1]), fmaxf(red[2], red[3]));
  float4 e;
  e.x = __expf(x.x - mx); e.y = __expf(x.y - mx);
  e.z = __expf(x.z - mx); e.w = __expf(x.w - mx);
  float sum = e.x + e.y + e.z + e.w;
  sum = wred_sum(sum);
  if (l == 0) red[4 + w] = sum;
  __syncthreads();
  sum = red[4] + red[5] + red[6] + red[7];
  const float inv = 1.f / sum;
  e.x *= inv; e.y *= inv; e.z *= inv; e.w *= inv;
  reinterpret_cast<float4*>(p0)[tid] = e;
}

// K3: partial c[ch][b][h][m] = sum_{s in chunk} attn[b][h][s] * values[s][b][m].
// attn chunk staged in LDS (broadcast reads); values streamed coalesced.
template <int NCH>
__global__ __launch_bounds__(256) void k3_cpart(const float* __restrict__ values,
                                                const float* __restrict__ attn,
                                                float* __restrict__ cp) {
  constexpr int SC = SLEN / NCH;
  __shared__ __align__(16) float al[NH * SC];
  const int b = blockIdx.x & 63;
  const int ch = blockIdx.x >> 6;
  const int s0 = ch * SC;
  const int tid = threadIdx.x;
  for (int f = tid; f < NH * SC / 4; f += 256) {
    int hh = f / (SC / 4), c4 = f % (SC / 4);
    *reinterpret_cast<float4*>(&al[hh * SC + c4 * 4]) =
        *reinterpret_cast<const float4*>(attn + ((size_t)b * NH + hh) * SLEN + s0 + c4 * 4);
  }
  __syncthreads();
  const int m4 = tid * 4;
  float4 acc[NH];
#pragma unroll
  for (int i = 0; i < NH; ++i) acc[i] = make_float4(0.f, 0.f, 0.f, 0.f);
  const float* vbase = values + ((size_t)s0 * NB + b) * DMODEL + m4;
#pragma unroll 2
  for (int sl = 0; sl < SC; sl += 4) {
    const float* vp = vbase + (size_t)sl * NB * DMODEL;
    float4 v0 = *reinterpret_cast<const float4*>(vp);
    float4 v1 = *reinterpret_cast<const float4*>(vp + (size_t)1 * NB * DMODEL);
    float4 v2 = *reinterpret_cast<const float4*>(vp + (size_t)2 * NB * DMODEL);
    float4 v3 = *reinterpret_cast<const float4*>(vp + (size_t)3 * NB * DMODEL);
#pragma unroll
    for (int hh = 0; hh < NH; ++hh) {
      float4 a = *reinterpret_cast<const float4*>(&al[hh * SC + sl]);  // broadcast
      FMA4_BCAST(acc[hh], a, v0, v1, v2, v3);
    }
  }
#pragma unroll
  for (int hh = 0; hh < NH; ++hh)
    *reinterpret_cast<float4*>(cp + (((size_t)ch * NB + b) * NH + hh) * DMODEL + m4) = acc[hh];
}

// K4: out[b][h*64+d] = sum_m Wk[h*64+d][m] * (sum_ch cp[ch][b][h][m]).
template <int NCH>
__global__ __launch_bounds__(256) void k4_out(const float* __restrict__ cp,
                                              const float* __restrict__ Wk,
                                              float* __restrict__ out) {
  __shared__ __align__(16) float cl[4 * DMODEL];
  const int h = blockIdx.x & 15;
  const int b0 = (blockIdx.x >> 4) * 4;
  const int tid = threadIdx.x, w = tid >> 6, l = tid & 63;
  for (int f = tid; f < 4 * DMODEL / 4; f += 256) {
    int bi = f >> 8, m4 = (f & 255) * 4;
    float4 s = make_float4(0.f, 0.f, 0.f, 0.f);
#pragma unroll
    for (int ch = 0; ch < NCH; ++ch) {
      float4 t = *reinterpret_cast<const float4*>(
          cp + (((size_t)ch * NB + b0 + bi) * NH + h) * DMODEL + m4);
      s.x += t.x; s.y += t.y; s.z += t.z; s.w += t.w;
    }
    *reinterpret_cast<float4*>(&cl[bi * DMODEL + m4]) = s;
  }
  __syncthreads();
  float4 c[4][4];
#pragma unroll
  for (int bi = 0; bi < 4; ++bi)
#pragma unroll
    for (int k = 0; k < 4; ++k)
      c[bi][k] = *reinterpret_cast<const float4*>(&cl[bi * DMODEL + l * 16 + k * 4]);
  for (int jj = 0; jj < 16; ++jj) {
    const int d = w * 16 + jj;
    const float4* wr = reinterpret_cast<const float4*>(Wk + (size_t)(h * HD + d) * DMODEL) + l * 4;
    const float4 w0 = wr[0], w1 = wr[1], w2 = wr[2], w3 = wr[3];
#pragma unroll
    for (int bi = 0; bi < 4; ++bi) {
      float s = 0.f;
      DOT4_ACC(s, w0, c[bi][0]); DOT4_ACC(s, w1, c[bi][1]);
      DOT4_ACC(s, w2, c[bi][2]); DOT4_ACC(s, w3, c[bi][3]);
      s = wred_sum(s);
      if (l == 0) out[(size_t)(b0 + bi) * (NH * HD) + h * HD + d] = s;
    }
  }
}

extern "C" void kernel_launch(void* const* d_in, const int* in_sizes, int n_in,
                              void* d_out, int out_size, void* d_ws, size_t ws_size,
                              hipStream_t stream) {
  const float* query  = (const float*)d_in[0];
  const float* keys   = (const float*)d_in[1];
  const float* values = (const float*)d_in[2];
  const float* Wq     = (const float*)d_in[3];
  const float* Wk     = (const float*)d_in[4];
  float* out = (float*)d_out;

  float* W   = (float*)d_ws;
  float* qp  = W;                                   // 64*1024
  float* qt  = qp + (size_t)NB * DMODEL;            // 64*16*1024
  float* sc0 = qt + (size_t)NB * NH * DMODEL;       // partial m-half 0 -> attn
  float* sc1 = sc0 + (size_t)NB * NH * SLEN;        // partial m-half 1
  float* cp  = sc1 + (size_t)NB * NH * SLEN;        // NCH*64*16*1024

  const size_t base_floats = (size_t)NB * DMODEL + (size_t)NB * NH * DMODEL
                           + 2 * (size_t)NB * NH * SLEN;

  k0_qp<<<256, 256, 0, stream>>>(query, Wq, qp);
  k1_qt<<<128, 256, 0, stream>>>(qp, Wk, qt);
  k2_scores<<<1024, 128, 0, stream>>>(keys, qt, sc0);  // writes sc0 (mh=0) and sc1 (mh=1)
  k_sm<<<NB * NH, 256, 0, stream>>>(sc0, sc1);

  const size_t chunk_floats = (size_t)NB * NH * DMODEL;
  if (ws_size >= (base_floats + 16 * chunk_floats) * sizeof(float)) {
    k3_cpart<16><<<16 * NB, 256, 0, stream>>>(values, sc0, cp);
    k4_out<16><<<NH * (NB / 4), 256, 0, stream>>>(cp, Wk, out);
  } else if (ws_size >= (base_floats + 8 * chunk_floats) * sizeof(float)) {
    k3_cpart<8><<<8 * NB, 256, 0, stream>>>(values, sc0, cp);
    k4_out<8><<<NH * (NB / 4), 256, 0, stream>>>(cp, Wk, out);
  } else if (ws_size >= (base_floats + 4 * chunk_floats) * sizeof(float)) {
    k3_cpart<4><<<4 * NB, 256, 0, stream>>>(values, sc0, cp);
    k4_out<4><<<NH * (NB / 4), 256, 0, stream>>>(cp, Wk, out);
  } else {
    k3_cpart<2><<<2 * NB, 256, 0, stream>>>(values, sc0, cp);
    k4_out<2><<<NH * (NB / 4), 256, 0, stream>>>(cp, Wk, out);
  }
}